// Round 1
// baseline (281.059 us; speedup 1.0000x reference)
//
#include <hip/hip_runtime.h>
#include <hip/hip_bf16.h>

#define N_NODES 100000
#define N_EDGES 1250000
#define D_FEAT  64

// One thread per (edge, feature). Wave = 64 lanes = one edge's full feature row:
// - x row read is one coalesced 256B transaction per wave
// - src/dst index loads are wave-uniform (same address broadcast)
// - 64 atomicAdds per wave hit 64 distinct dwords in 2 consecutive cachelines
__global__ void mp_scatter_kernel(const float* __restrict__ x,
                                  const int* __restrict__ src,
                                  const int* __restrict__ dst,
                                  float* __restrict__ out) {
    long long t = (long long)blockIdx.x * blockDim.x + threadIdx.x;
    long long e = t >> 6;          // edge id
    int f = (int)(t & 63);         // feature id = lane
    if (e >= N_EDGES) return;
    int s = src[e];
    int d = dst[e];
    float v = x[(long long)s * D_FEAT + f];
    atomicAdd(&out[(long long)d * D_FEAT + f], v);
}

extern "C" void kernel_launch(void* const* d_in, const int* in_sizes, int n_in,
                              void* d_out, int out_size, void* d_ws, size_t ws_size,
                              hipStream_t stream) {
    const float* x   = (const float*)d_in[0];
    const int*   ei  = (const int*)d_in[1];      // (2, N_EDGES): row 0 = src, row 1 = dst
    const int*   src = ei;
    const int*   dst = ei + N_EDGES;
    float* out = (float*)d_out;

    // Harness poisons d_out (0xAA) once and never re-poisons between timed
    // replays -> must zero it ourselves every call.
    hipMemsetAsync(out, 0, (size_t)out_size * sizeof(float), stream);

    long long total = (long long)N_EDGES * D_FEAT;   // 80M threads
    int block = 256;
    long long grid = (total + block - 1) / block;
    mp_scatter_kernel<<<(dim3)(unsigned)grid, block, 0, stream>>>(x, src, dst, out);
}

// Round 3
// 171.730 us; speedup vs baseline: 1.6366x; 1.6366x over previous
//
#include <hip/hip_runtime.h>
#include <hip/hip_bf16.h>

#define N_NODES 100000
#define N_EDGES 1250000
#define D_FEAT  64
#define CAP     32   // slot capacity per node; Poisson(12.5) tail past 32 -> spill

// ---------------- bucket pipeline ----------------
// ws int layout:
//   [0, N_NODES)              counts (zeroed per call)
//   [N_NODES]                 spill counter (zeroed per call)
//   [N_NODES+1, +N_EDGES)     spill list (edge ids)
//   [SLOTS_OFF, +N_NODES*CAP) slots: src ids bucketed by dst

__global__ __launch_bounds__(256)
void k_scatter(const int* __restrict__ src, const int* __restrict__ dst,
               int* __restrict__ counts, int* __restrict__ slots,
               int* __restrict__ spill_cnt, int* __restrict__ spill_list) {
    int e = blockIdx.x * blockDim.x + threadIdx.x;
    if (e >= N_EDGES) return;
    int d = dst[e];
    int pos = atomicAdd(&counts[d], 1);
    if (pos < CAP) {
        slots[d * CAP + pos] = src[e];
    } else {
        int sp = atomicAdd(spill_cnt, 1);
        spill_list[sp] = e;
    }
}

__global__ __launch_bounds__(256)
void k_gather(const float* __restrict__ x, const int* __restrict__ counts,
              const int* __restrict__ slots, float* __restrict__ out) {
    int t = blockIdx.x * blockDim.x + threadIdx.x;
    int n = t >> 6;            // node id (one wave per node)
    int lane = t & 63;         // feature id
    if (n >= N_NODES) return;
    int c = counts[n];
    c = c > CAP ? CAP : c;
    const int* sl = slots + n * CAP;
    float acc = 0.f;
    int j = 0;
    for (; j + 2 <= c; j += 2) {          // 2-way ILP on the gather chain
        int s0 = sl[j], s1 = sl[j + 1];
        float v0 = x[s0 * D_FEAT + lane];
        float v1 = x[s1 * D_FEAT + lane];
        acc += v0;
        acc += v1;
    }
    if (j < c) acc += x[sl[j] * D_FEAT + lane];
    out[n * D_FEAT + lane] = acc;         // full overwrite -> no out memset
}

__global__ __launch_bounds__(256)
void k_spill(const float* __restrict__ x, const int* __restrict__ src,
             const int* __restrict__ dst, const int* __restrict__ spill_cnt,
             const int* __restrict__ spill_list, float* __restrict__ out) {
    int total = (*spill_cnt) * D_FEAT;    // usually 0
    int stride = gridDim.x * blockDim.x;
    for (int i = blockIdx.x * blockDim.x + threadIdx.x; i < total; i += stride) {
        int e = spill_list[i >> 6];
        int f = i & 63;
        atomicAdd(&out[dst[e] * D_FEAT + f], x[src[e] * D_FEAT + f]);
    }
}

// ---------------- fallback: round-1 atomic kernel ----------------
__global__ __launch_bounds__(256)
void mp_scatter_atomic(const float* __restrict__ x,
                       const int* __restrict__ src,
                       const int* __restrict__ dst,
                       float* __restrict__ out) {
    long long t = (long long)blockIdx.x * blockDim.x + threadIdx.x;
    long long e = t >> 6;
    int f = (int)(t & 63);
    if (e >= N_EDGES) return;
    atomicAdd(&out[(long long)dst[e] * D_FEAT + f],
              x[(long long)src[e] * D_FEAT + f]);
}

extern "C" void kernel_launch(void* const* d_in, const int* in_sizes, int n_in,
                              void* d_out, int out_size, void* d_ws, size_t ws_size,
                              hipStream_t stream) {
    const float* x   = (const float*)d_in[0];
    const int*   ei  = (const int*)d_in[1];   // (2, N_EDGES): row 0 = src, row 1 = dst
    const int*   src = ei;
    const int*   dst = ei + N_EDGES;
    float* out = (float*)d_out;

    const size_t SPILL_OFF = (size_t)N_NODES + 1;                 // ints
    const size_t SLOTS_OFF = (SPILL_OFF + N_EDGES + 63) & ~63ull; // ints, 256B-align
    const size_t WS_INTS   = SLOTS_OFF + (size_t)N_NODES * CAP;
    const size_t WS_BYTES  = WS_INTS * sizeof(int);               // ~18.2 MB

    if (ws_size >= WS_BYTES) {
        int* wsi        = (int*)d_ws;
        int* counts     = wsi;
        int* spill_cnt  = wsi + N_NODES;
        int* spill_list = wsi + SPILL_OFF;
        int* slots      = wsi + SLOTS_OFF;

        // zero counts + spill counter (contiguous)
        hipMemsetAsync(counts, 0, (size_t)(N_NODES + 1) * sizeof(int), stream);

        int block = 256;
        int grid_s = (N_EDGES + block - 1) / block;
        k_scatter<<<grid_s, block, 0, stream>>>(src, dst, counts, slots,
                                                spill_cnt, spill_list);

        long long gt = (long long)N_NODES * D_FEAT;
        int grid_g = (int)((gt + block - 1) / block);
        k_gather<<<grid_g, block, 0, stream>>>(x, counts, slots, out);

        k_spill<<<64, block, 0, stream>>>(x, src, dst, spill_cnt, spill_list, out);
    } else {
        // fallback: direct atomic scatter (requires zeroed out)
        hipMemsetAsync(out, 0, (size_t)out_size * sizeof(float), stream);
        long long total = (long long)N_EDGES * D_FEAT;
        int block = 256;
        long long grid = (total + block - 1) / block;
        mp_scatter_atomic<<<(dim3)(unsigned)grid, block, 0, stream>>>(x, src, dst, out);
    }
}